// Round 1
// baseline (257.361 us; speedup 1.0000x reference)
//
#include <hip/hip_runtime.h>

#define TT 4
#define BB 32
#define CC 256
#define NN 256
#define EPSf 1e-5f
#define MULTf 0.35355339059327373f

// ---------------------------------------------------------------------------
// K1: xs = lif(x).  One thread per (b,c,n), sequential over t.
// LIF: v += (x - v)/2 ; s = (v >= 1) ; v = s ? 0 : v
// Halving is exact in f32, so this recurrence is bitwise-stable.
// ---------------------------------------------------------------------------
__global__ __launch_bounds__(256) void k_lif_x(const float* __restrict__ x,
                                               unsigned char* __restrict__ xs) {
#pragma clang fp contract(off)
  int idx = blockIdx.x * 256 + threadIdx.x;  // over B*C*N = 2097152
  const int stride = BB * CC * NN;
  float v = 0.0f;
#pragma unroll
  for (int t = 0; t < TT; ++t) {
    float xt = x[(size_t)t * stride + idx];
    float d = (xt - v) * 0.5f;
    v = v + d;
    bool s = (v >= 1.0f);
    xs[(size_t)t * stride + idx] = s ? (unsigned char)1 : (unsigned char)0;
    if (s) v = 0.0f;
  }
}

// ---------------------------------------------------------------------------
// K2: fused q/k/v conv1x1 + BN + LIF.
// Output tile: 64 tokens (n) x 64 out-channels, all T in-register for LIF.
// Fused oc space: [0,256)=q, [256,512)=k, [512,768)=v.
// ---------------------------------------------------------------------------
__global__ __launch_bounds__(256) void k_qkv(
    const unsigned char* __restrict__ xs,
    const float* __restrict__ qw, const float* __restrict__ kw, const float* __restrict__ vw,
    const float* __restrict__ qga, const float* __restrict__ qbe, const float* __restrict__ qme, const float* __restrict__ qva,
    const float* __restrict__ kga, const float* __restrict__ kbe, const float* __restrict__ kme, const float* __restrict__ kva,
    const float* __restrict__ vga, const float* __restrict__ vbe, const float* __restrict__ vme, const float* __restrict__ vva,
    unsigned char* __restrict__ qkv) {
  __shared__ float Alds[64][68];
  __shared__ float Wt[64][68];
  const int tid = threadIdx.x;
  const int oc0 = blockIdx.x * 64;   // 0..704
  const int n0 = blockIdx.y * 64;    // 0..192
  const int b = blockIdx.z;          // 0..31
  const int sel = oc0 >> 8;          // 0=q 1=k 2=v
  const float* W = sel == 0 ? qw : (sel == 1 ? kw : vw);
  const float* G = sel == 0 ? qga : (sel == 1 ? kga : vga);
  const float* Be = sel == 0 ? qbe : (sel == 1 ? kbe : vbe);
  const float* Mn = sel == 0 ? qme : (sel == 1 ? kme : vme);
  const float* Vr = sel == 0 ? qva : (sel == 1 ? kva : vva);
  const int ocbase = oc0 & 255;

  const int tn = tid & 15;   // n group: n = n0 + tn*4 + {0..3}
  const int to = tid >> 4;   // oc group: oc = oc0 + to*4 + {0..3}

  float inv_[4], mean_[4], beta_[4];
#pragma unroll
  for (int j = 0; j < 4; ++j) {
    int oc = ocbase + to * 4 + j;
    inv_[j] = G[oc] / sqrtf(Vr[oc] + EPSf);
    mean_[j] = Mn[oc];
    beta_[j] = Be[oc];
  }
  float vst[16];
#pragma unroll
  for (int i = 0; i < 16; ++i) vst[i] = 0.0f;

  const int arow = tid >> 2;         // 0..63
  const int aseg = (tid & 3) * 16;   // 0,16,32,48

  for (int t = 0; t < TT; ++t) {
    float acc[16];
#pragma unroll
    for (int i = 0; i < 16; ++i) acc[i] = 0.0f;

    for (int ck = 0; ck < 4; ++ck) {
      const int c0 = ck * 64;
      __syncthreads();
      // stage A[ci][ni] = xs[t,b,c0+ci,n0+ni]  (u8 -> f32)
      {
        const unsigned char* src =
            xs + ((size_t)(t * BB + b) * CC + (c0 + arow)) * NN + n0 + aseg;
        uint4 u = *reinterpret_cast<const uint4*>(src);
        const unsigned char* p = reinterpret_cast<const unsigned char*>(&u);
#pragma unroll
        for (int kb = 0; kb < 16; ++kb) Alds[arow][aseg + kb] = (float)p[kb];
      }
      // stage Wt[ci][oi] = W[ocbase+oi][c0+ci]  (transposed)
      {
        const float* wsrc = W + (size_t)(ocbase + arow) * CC + c0 + aseg;
#pragma unroll
        for (int q4 = 0; q4 < 4; ++q4) {
          float4 w4 = *reinterpret_cast<const float4*>(wsrc + q4 * 4);
          Wt[aseg + q4 * 4 + 0][arow] = w4.x;
          Wt[aseg + q4 * 4 + 1][arow] = w4.y;
          Wt[aseg + q4 * 4 + 2][arow] = w4.z;
          Wt[aseg + q4 * 4 + 3][arow] = w4.w;
        }
      }
      __syncthreads();
#pragma unroll 8
      for (int ci = 0; ci < 64; ++ci) {
        float4 a4 = *reinterpret_cast<const float4*>(&Alds[ci][tn * 4]);
        float4 w4 = *reinterpret_cast<const float4*>(&Wt[ci][to * 4]);
        acc[0]  = fmaf(w4.x, a4.x, acc[0]);
        acc[1]  = fmaf(w4.x, a4.y, acc[1]);
        acc[2]  = fmaf(w4.x, a4.z, acc[2]);
        acc[3]  = fmaf(w4.x, a4.w, acc[3]);
        acc[4]  = fmaf(w4.y, a4.x, acc[4]);
        acc[5]  = fmaf(w4.y, a4.y, acc[5]);
        acc[6]  = fmaf(w4.y, a4.z, acc[6]);
        acc[7]  = fmaf(w4.y, a4.w, acc[7]);
        acc[8]  = fmaf(w4.z, a4.x, acc[8]);
        acc[9]  = fmaf(w4.z, a4.y, acc[9]);
        acc[10] = fmaf(w4.z, a4.z, acc[10]);
        acc[11] = fmaf(w4.z, a4.w, acc[11]);
        acc[12] = fmaf(w4.w, a4.x, acc[12]);
        acc[13] = fmaf(w4.w, a4.y, acc[13]);
        acc[14] = fmaf(w4.w, a4.z, acc[14]);
        acc[15] = fmaf(w4.w, a4.w, acc[15]);
      }
    }
    // BN + LIF epilogue (no fma contraction: mirror reference op order)
    {
#pragma clang fp contract(off)
      unsigned char* dst = qkv + ((size_t)(t * BB + b) * 768) * NN;
#pragma unroll
      for (int j = 0; j < 4; ++j) {
#pragma unroll
        for (int i2 = 0; i2 < 4; ++i2) {
          float xm = acc[j * 4 + i2] - mean_[j];
          float y = xm * inv_[j];
          y = y + beta_[j];
          float v = vst[j * 4 + i2];
          float d = (y - v) * 0.5f;
          v = v + d;
          bool s = (v >= 1.0f);
          dst[(size_t)(oc0 + to * 4 + j) * NN + n0 + tn * 4 + i2] =
              s ? (unsigned char)1 : (unsigned char)0;
          vst[j * 4 + i2] = s ? 0.0f : v;
        }
      }
    }
  }
}

// ---------------------------------------------------------------------------
// K3: attention via (Q (K^T V)) * (2*scale), then LIF -> attn_spike.
// Exact integer arithmetic throughout (spikes are binary), so the result is
// bitwise identical to the reference's (QK^T)V.
// One block per (b,h); bit-packed spikes; popcount inner products.
// ---------------------------------------------------------------------------
__device__ __forceinline__ unsigned int pack32(const unsigned char* p) {
  const uint4 u0 = *reinterpret_cast<const uint4*>(p);
  const uint4 u1 = *reinterpret_cast<const uint4*>(p + 16);
  unsigned int ws[8] = {u0.x, u0.y, u0.z, u0.w, u1.x, u1.y, u1.z, u1.w};
  unsigned int m = 0;
#pragma unroll
  for (int w = 0; w < 8; ++w) {
    unsigned int xw = ws[w] & 0x01010101u;
    unsigned int nib = (xw | (xw >> 7) | (xw >> 14) | (xw >> 21)) & 0xFu;
    m |= nib << (4 * w);
  }
  return m;
}

__global__ __launch_bounds__(256) void k_attn(const unsigned char* __restrict__ qkv,
                                              unsigned char* __restrict__ attn_s) {
  __shared__ unsigned int Qb[32][9], Kb[32][9], Vb[32][9];
  __shared__ int KtV[32][36];
  const int tid = threadIdx.x;
  const int b = blockIdx.x >> 3;
  const int h = blockIdx.x & 7;
  const int i = tid >> 3;   // channel-in-head 0..31 (staging)
  const int seg = tid & 7;  // 32-byte spatial segment (staging)
  const int n = tid;        // spatial token (compute)

  float vst[32];
#pragma unroll
  for (int j = 0; j < 32; ++j) vst[j] = 0.0f;

  for (int t = 0; t < TT; ++t) {
    __syncthreads();
    const unsigned char* base = qkv + (size_t)(t * BB + b) * 768 * NN;
    Qb[i][seg] = pack32(base + (size_t)(h * 32 + i) * NN + seg * 32);
    Kb[i][seg] = pack32(base + (size_t)(256 + h * 32 + i) * NN + seg * 32);
    Vb[i][seg] = pack32(base + (size_t)(512 + h * 32 + i) * NN + seg * 32);
    __syncthreads();
    // KtV[i][j] = sum_m K[m,i]*V[m,j]
#pragma unroll
    for (int p = 0; p < 4; ++p) {
      int e = tid + p * 256;
      int ii = e >> 5, jj = e & 31;
      int s = 0;
#pragma unroll
      for (int w = 0; w < 8; ++w) s += __popc(Kb[ii][w] & Vb[jj][w]);
      KtV[ii][jj] = s;
    }
    __syncthreads();
    // out[n][j] = sum_i Q[n,i] * KtV[i][j]
    int acc[32];
#pragma unroll
    for (int j = 0; j < 32; ++j) acc[j] = 0;
    for (int ii = 0; ii < 32; ++ii) {
      unsigned int qbit = (Qb[ii][n >> 5] >> (n & 31)) & 1u;
      if (qbit) {
        const int4* row = reinterpret_cast<const int4*>(&KtV[ii][0]);
#pragma unroll
        for (int j4 = 0; j4 < 8; ++j4) {
          int4 kk = row[j4];
          acc[j4 * 4 + 0] += kk.x;
          acc[j4 * 4 + 1] += kk.y;
          acc[j4 * 4 + 2] += kk.z;
          acc[j4 * 4 + 3] += kk.w;
        }
      }
    }
    // scale + LIF + store spike
    {
#pragma clang fp contract(off)
      unsigned char* dst = attn_s + ((size_t)(t * BB + b) * 256 + h * 32) * NN + n;
#pragma unroll
      for (int j = 0; j < 32; ++j) {
        float y = (float)acc[j] * MULTf;
        float v = vst[j];
        float d = (y - v) * 0.5f;
        v = v + d;
        bool s = (v >= 1.0f);
        dst[(size_t)j * NN] = s ? (unsigned char)1 : (unsigned char)0;
        vst[j] = s ? 0.0f : v;
      }
    }
  }
}

// ---------------------------------------------------------------------------
// K4: proj conv1x1 + BN -> d_out (f32).  Same tiling as K2, no LIF, t in grid.
// ---------------------------------------------------------------------------
__global__ __launch_bounds__(256) void k_proj(const unsigned char* __restrict__ attn_s,
                                              const float* __restrict__ pw,
                                              const float* __restrict__ pga,
                                              const float* __restrict__ pbe,
                                              const float* __restrict__ pme,
                                              const float* __restrict__ pva,
                                              float* __restrict__ out) {
  __shared__ float Alds[64][68];
  __shared__ float Wt[64][68];
  const int tid = threadIdx.x;
  const int oc0 = blockIdx.x * 64;  // 0..192
  const int n0 = blockIdx.y * 64;
  const int tb = blockIdx.z;  // t*32+b, 0..127
  const int tn = tid & 15;
  const int to = tid >> 4;

  float inv_[4], mean_[4], beta_[4];
#pragma unroll
  for (int j = 0; j < 4; ++j) {
    int oc = oc0 + to * 4 + j;
    inv_[j] = pga[oc] / sqrtf(pva[oc] + EPSf);
    mean_[j] = pme[oc];
    beta_[j] = pbe[oc];
  }
  const int arow = tid >> 2;
  const int aseg = (tid & 3) * 16;

  float acc[16];
#pragma unroll
  for (int i = 0; i < 16; ++i) acc[i] = 0.0f;

  for (int ck = 0; ck < 4; ++ck) {
    const int c0 = ck * 64;
    __syncthreads();
    {
      const unsigned char* src =
          attn_s + ((size_t)tb * CC + (c0 + arow)) * NN + n0 + aseg;
      uint4 u = *reinterpret_cast<const uint4*>(src);
      const unsigned char* p = reinterpret_cast<const unsigned char*>(&u);
#pragma unroll
      for (int kb = 0; kb < 16; ++kb) Alds[arow][aseg + kb] = (float)p[kb];
    }
    {
      const float* wsrc = pw + (size_t)(oc0 + arow) * CC + c0 + aseg;
#pragma unroll
      for (int q4 = 0; q4 < 4; ++q4) {
        float4 w4 = *reinterpret_cast<const float4*>(wsrc + q4 * 4);
        Wt[aseg + q4 * 4 + 0][arow] = w4.x;
        Wt[aseg + q4 * 4 + 1][arow] = w4.y;
        Wt[aseg + q4 * 4 + 2][arow] = w4.z;
        Wt[aseg + q4 * 4 + 3][arow] = w4.w;
      }
    }
    __syncthreads();
#pragma unroll 8
    for (int ci = 0; ci < 64; ++ci) {
      float4 a4 = *reinterpret_cast<const float4*>(&Alds[ci][tn * 4]);
      float4 w4 = *reinterpret_cast<const float4*>(&Wt[ci][to * 4]);
      acc[0]  = fmaf(w4.x, a4.x, acc[0]);
      acc[1]  = fmaf(w4.x, a4.y, acc[1]);
      acc[2]  = fmaf(w4.x, a4.z, acc[2]);
      acc[3]  = fmaf(w4.x, a4.w, acc[3]);
      acc[4]  = fmaf(w4.y, a4.x, acc[4]);
      acc[5]  = fmaf(w4.y, a4.y, acc[5]);
      acc[6]  = fmaf(w4.y, a4.z, acc[6]);
      acc[7]  = fmaf(w4.y, a4.w, acc[7]);
      acc[8]  = fmaf(w4.z, a4.x, acc[8]);
      acc[9]  = fmaf(w4.z, a4.y, acc[9]);
      acc[10] = fmaf(w4.z, a4.z, acc[10]);
      acc[11] = fmaf(w4.z, a4.w, acc[11]);
      acc[12] = fmaf(w4.w, a4.x, acc[12]);
      acc[13] = fmaf(w4.w, a4.y, acc[13]);
      acc[14] = fmaf(w4.w, a4.z, acc[14]);
      acc[15] = fmaf(w4.w, a4.w, acc[15]);
    }
  }
  {
#pragma clang fp contract(off)
#pragma unroll
    for (int j = 0; j < 4; ++j) {
      float r[4];
#pragma unroll
      for (int i2 = 0; i2 < 4; ++i2) {
        float xm = acc[j * 4 + i2] - mean_[j];
        float y = xm * inv_[j];
        r[i2] = y + beta_[j];
      }
      float* po = out + ((size_t)tb * CC + oc0 + to * 4 + j) * NN + n0 + tn * 4;
      *reinterpret_cast<float4*>(po) = make_float4(r[0], r[1], r[2], r[3]);
    }
  }
}

// ---------------------------------------------------------------------------
extern "C" void kernel_launch(void* const* d_in, const int* in_sizes, int n_in,
                              void* d_out, int out_size, void* d_ws, size_t ws_size,
                              hipStream_t stream) {
  const float* x = (const float*)d_in[0];
  const float* q_w = (const float*)d_in[1];
  const float* q_g = (const float*)d_in[2];
  const float* q_b = (const float*)d_in[3];
  const float* q_m = (const float*)d_in[4];
  const float* q_v = (const float*)d_in[5];
  const float* k_w = (const float*)d_in[6];
  const float* k_g = (const float*)d_in[7];
  const float* k_b = (const float*)d_in[8];
  const float* k_m = (const float*)d_in[9];
  const float* k_v = (const float*)d_in[10];
  const float* v_w = (const float*)d_in[11];
  const float* v_g = (const float*)d_in[12];
  const float* v_b = (const float*)d_in[13];
  const float* v_m = (const float*)d_in[14];
  const float* v_v = (const float*)d_in[15];
  const float* p_w = (const float*)d_in[16];
  const float* p_g = (const float*)d_in[17];
  const float* p_b = (const float*)d_in[18];
  const float* p_m = (const float*)d_in[19];
  const float* p_v = (const float*)d_in[20];

  unsigned char* xs = (unsigned char*)d_ws;                 // 8 MiB  (T*B*C*N)
  unsigned char* qkv = xs + (size_t)TT * BB * CC * NN;      // 24 MiB (T*B*768*N)
  unsigned char* attn = qkv + (size_t)TT * BB * 768 * NN;   // 8 MiB

  float* out = (float*)d_out;

  k_lif_x<<<dim3(BB * CC * NN / 256), 256, 0, stream>>>(x, xs);
  k_qkv<<<dim3(12, 4, 32), 256, 0, stream>>>(xs, q_w, k_w, v_w,
                                             q_g, q_b, q_m, q_v,
                                             k_g, k_b, k_m, k_v,
                                             v_g, v_b, v_m, v_v, qkv);
  k_attn<<<dim3(256), 256, 0, stream>>>(qkv, attn);
  k_proj<<<dim3(4, 4, 128), 256, 0, stream>>>(attn, p_w, p_g, p_b, p_m, p_v, out);
}

// Round 2
// 168.681 us; speedup vs baseline: 1.5257x; 1.5257x over previous
//
#include <hip/hip_runtime.h>

#define TT 4
#define BB 32
#define CC 256
#define NN 256
#define EPSf 1e-5f
#define MULTf 0.35355339059327373f
#define MARGINf 3e-3f
#define FLAG_CAP 524288u

typedef __attribute__((ext_vector_type(8))) short s16x8;
typedef __attribute__((ext_vector_type(4))) float f32x4;
typedef unsigned char uchar;
typedef unsigned int uint;
typedef unsigned short ushort;

// bf16 round-to-nearest-even (no NaN handling needed here)
__device__ __forceinline__ ushort f2bf_rn(float f) {
  uint u = __float_as_uint(f);
  u = (u + 0x7FFFu + ((u >> 16) & 1u)) >> 16;
  return (ushort)u;
}
__device__ __forceinline__ float bf2f(ushort b) {
  return __uint_as_float(((uint)b) << 16);
}

__device__ __forceinline__ void gload_lds16(const void* g, void* l) {
  __builtin_amdgcn_global_load_lds(
      (const __attribute__((address_space(1))) uint*)g,
      (__attribute__((address_space(3))) uint*)l, 16, 0, 0);
}

// ---------------------------------------------------------------------------
// K1: xs = lif(x), float4-vectorized. Bitwise-exact (halving is exact).
// ---------------------------------------------------------------------------
__global__ __launch_bounds__(256) void k_lif_x(const float* __restrict__ x,
                                               uchar* __restrict__ xs) {
#pragma clang fp contract(off)
  const int q = blockIdx.x * 256 + threadIdx.x;  // quad index over B*C*N/4
  const size_t stride = (size_t)BB * CC * NN;
  float v0 = 0.f, v1 = 0.f, v2 = 0.f, v3 = 0.f;
#pragma unroll
  for (int t = 0; t < TT; ++t) {
    float4 xt = *reinterpret_cast<const float4*>(x + t * stride + (size_t)q * 4);
    uchar s0, s1, s2, s3;
    v0 = v0 + (xt.x - v0) * 0.5f; s0 = v0 >= 1.0f; if (s0) v0 = 0.f;
    v1 = v1 + (xt.y - v1) * 0.5f; s1 = v1 >= 1.0f; if (s1) v1 = 0.f;
    v2 = v2 + (xt.z - v2) * 0.5f; s2 = v2 >= 1.0f; if (s2) v2 = 0.f;
    v3 = v3 + (xt.w - v3) * 0.5f; s3 = v3 >= 1.0f; if (s3) v3 = 0.f;
    uchar4 o; o.x = s0; o.y = s1; o.z = s2; o.w = s3;
    *reinterpret_cast<uchar4*>(xs + t * stride + (size_t)q * 4) = o;
  }
}

// ---------------------------------------------------------------------------
// K2: weight prep — 2-way bf16 split, MFMA-fragment-ready layout:
//   wF[s][ob][ks][lane][j]  = split_s( W[ob*16 + (lane&15)][ks*32 + (lane>>4)*8 + j] )
// qkv: 48 ob (q 0-15, k 16-31, v 32-47); proj: 16 ob.
// ---------------------------------------------------------------------------
__global__ __launch_bounds__(256) void k_prep_w(
    const float* __restrict__ qw, const float* __restrict__ kw,
    const float* __restrict__ vw, const float* __restrict__ pw,
    uchar* __restrict__ wfq, uchar* __restrict__ wfp) {
  const int gid = blockIdx.x * 256 + threadIdx.x;  // 0..32767
  const int ob2 = gid >> 9;       // 0..63
  const int e = gid & 511;
  const int ks = e >> 6, l = e & 63;
  const float* W;
  uchar* outb;
  int ob_out, nob;
  if (ob2 < 48) {
    const int sel = ob2 >> 4;
    W = sel == 0 ? qw : (sel == 1 ? kw : vw);
    W += ((size_t)((ob2 & 15) * 16 + (l & 15))) * CC;
    outb = wfq; ob_out = ob2; nob = 48;
  } else {
    W = pw + ((size_t)((ob2 - 48) * 16 + (l & 15))) * CC;
    outb = wfp; ob_out = ob2 - 48; nob = 16;
  }
  const int c0 = ks * 32 + (l >> 4) * 8;
  float wv[8];
  *reinterpret_cast<float4*>(&wv[0]) = *reinterpret_cast<const float4*>(W + c0);
  *reinterpret_cast<float4*>(&wv[4]) = *reinterpret_cast<const float4*>(W + c0 + 4);
  ushort hi[8], lo[8];
#pragma unroll
  for (int j = 0; j < 8; ++j) {
    hi[j] = f2bf_rn(wv[j]);
    lo[j] = f2bf_rn(wv[j] - bf2f(hi[j]));
  }
  const size_t base = (((size_t)ob_out * 8 + ks) * 64 + l) * 16;
  const size_t sstr = (size_t)nob * 8 * 64 * 16;
  *reinterpret_cast<uint4*>(outb + base) = *reinterpret_cast<const uint4*>(hi);
  *reinterpret_cast<uint4*>(outb + sstr + base) = *reinterpret_cast<const uint4*>(lo);
}

// ---------------------------------------------------------------------------
// K3: fragment xs spikes into bf16 B-operand chunks:
//   xsF[t][b][nb][ks][lane][j] = bf16( xs[t,b, ks*32+(lane>>4)*8+j, nb*16+(lane&15)] )
// ---------------------------------------------------------------------------
__global__ __launch_bounds__(256) void k_fragx(const uchar* __restrict__ xs,
                                               uchar* __restrict__ xsF) {
  const int tb = blockIdx.x >> 1;
  const int e = (blockIdx.x & 1) * 256 + threadIdx.x;  // 0..511
  const int nb = e & 15, lhi = (e >> 4) & 3, ks = e >> 6;
  const uchar* src = xs + (size_t)tb * 65536 + ((size_t)(ks * 32 + lhi * 8)) * 256 + nb * 16;
  uint4 r[8];
#pragma unroll
  for (int j = 0; j < 8; ++j)
    r[j] = *reinterpret_cast<const uint4*>(src + (size_t)j * 256);
  uint4* dst = reinterpret_cast<uint4*>(xsF) + (size_t)tb * 8192 + nb * 512 + ks * 64 + lhi * 16;
#pragma unroll
  for (int llo = 0; llo < 16; ++llo) {
    uint w[4];
#pragma unroll
    for (int p = 0; p < 4; ++p) {
      uint b0 = (reinterpret_cast<const uint*>(&r[2 * p    ])[llo >> 2] >> ((llo & 3) * 8)) & 1u;
      uint b1 = (reinterpret_cast<const uint*>(&r[2 * p + 1])[llo >> 2] >> ((llo & 3) * 8)) & 1u;
      w[p] = (b0 ? 0x3F80u : 0u) | (b1 ? 0x3F800000u : 0u);
    }
    uint4 o; o.x = w[0]; o.y = w[1]; o.z = w[2]; o.w = w[3];
    dst[llo] = o;
  }
}

// ---------------------------------------------------------------------------
// K4: fused q/k/v conv (MFMA, 2-split bf16) + BN + LIF -> bit-packed spikes
//     + near-threshold flags for the exact fixer.
// Block: 64oc x 64n, 4 waves (wave = 32x32), all T in-register.
// ---------------------------------------------------------------------------
__global__ __launch_bounds__(256, 2) void k_qkv_mfma(
    const uchar* __restrict__ xsF, const uchar* __restrict__ wfq,
    const float* __restrict__ qga, const float* __restrict__ qbe, const float* __restrict__ qme, const float* __restrict__ qva,
    const float* __restrict__ kga, const float* __restrict__ kbe, const float* __restrict__ kme, const float* __restrict__ kva,
    const float* __restrict__ vga, const float* __restrict__ vbe, const float* __restrict__ vme, const float* __restrict__ vva,
    ushort* __restrict__ qp, uint* __restrict__ flags) {
  __shared__ short lsB[4][8][64][8];  // [nb_local][ks][lane][8] = 32KB
  const int tid = threadIdx.x;
  const int w = tid >> 6, lane = tid & 63;
  const int lhi = lane >> 4, llo = lane & 15;
  const int wr = w >> 1, wc = w & 1;
  const int oc0 = blockIdx.x * 64;
  const int ntile = blockIdx.y;
  const int b = blockIdx.z;
  const int sel = oc0 >> 8;
  const float* G  = sel == 0 ? qga : (sel == 1 ? kga : vga);
  const float* Be = sel == 0 ? qbe : (sel == 1 ? kbe : vbe);
  const float* Mn = sel == 0 ? qme : (sel == 1 ? kme : vme);
  const float* Vr = sel == 0 ? qva : (sel == 1 ? kva : vva);

  // W fragments in registers (128 VGPR)
  s16x8 wfr[2][2][8];
#pragma unroll
  for (int s = 0; s < 2; ++s)
#pragma unroll
    for (int mf = 0; mf < 2; ++mf) {
      const int ob = blockIdx.x * 4 + wr * 2 + mf;
#pragma unroll
      for (int ks = 0; ks < 8; ++ks)
        wfr[s][mf][ks] = *reinterpret_cast<const s16x8*>(
            wfq + ((((size_t)s * 48 + ob) * 8 + ks) * 64 + lane) * 16);
    }

  float inv8[2][4], mean8[2][4], beta8[2][4];
#pragma unroll
  for (int mf = 0; mf < 2; ++mf)
#pragma unroll
    for (int r = 0; r < 4; ++r) {
      const int ocb = (oc0 & 255) + wr * 32 + mf * 16 + lhi * 4 + r;
      inv8[mf][r] = G[ocb] / sqrtf(Vr[ocb] + EPSf);
      mean8[mf][r] = Mn[ocb];
      beta8[mf][r] = Be[ocb];
    }

  float vst[2][2][4];
#pragma unroll
  for (int mf = 0; mf < 2; ++mf)
#pragma unroll
    for (int nf = 0; nf < 2; ++nf)
#pragma unroll
      for (int r = 0; r < 4; ++r) vst[mf][nf][r] = 0.f;
  uint fl = 0;

  for (int t = 0; t < TT; ++t) {
    __syncthreads();
    const uchar* src = xsF + (((size_t)(t * BB + b) * 16 + ntile * 4) * 8192);
#pragma unroll
    for (int k2 = 0; k2 < 8; ++k2) {
      const int chunk = w * 8 + k2;
      gload_lds16(src + (size_t)chunk * 1024 + lane * 16,
                  reinterpret_cast<char*>(&lsB[0][0][0][0]) + chunk * 1024);
    }
    __syncthreads();

    f32x4 acc[2][2];
#pragma unroll
    for (int mf = 0; mf < 2; ++mf)
#pragma unroll
      for (int nf = 0; nf < 2; ++nf) acc[mf][nf] = (f32x4){0.f, 0.f, 0.f, 0.f};

#pragma unroll
    for (int ks = 0; ks < 8; ++ks) {
      s16x8 b0 = *reinterpret_cast<const s16x8*>(&lsB[wc * 2][ks][lane][0]);
      s16x8 b1 = *reinterpret_cast<const s16x8*>(&lsB[wc * 2 + 1][ks][lane][0]);
#pragma unroll
      for (int s = 0; s < 2; ++s)
#pragma unroll
        for (int mf = 0; mf < 2; ++mf) {
          acc[mf][0] = __builtin_amdgcn_mfma_f32_16x16x32_bf16(wfr[s][mf][ks], b0, acc[mf][0], 0, 0, 0);
          acc[mf][1] = __builtin_amdgcn_mfma_f32_16x16x32_bf16(wfr[s][mf][ks], b1, acc[mf][1], 0, 0, 0);
        }
    }

    // BN + LIF + packed-spike write + margin flags
    ushort* qrow = qp + (size_t)(t * BB + b) * 768 * 16;
#pragma unroll
    for (int mf = 0; mf < 2; ++mf)
#pragma unroll
      for (int nf = 0; nf < 2; ++nf)
#pragma unroll
        for (int r = 0; r < 4; ++r) {
          float y = (acc[mf][nf][r] - mean8[mf][r]) * inv8[mf][r] + beta8[mf][r];
          float v = vst[mf][nf][r];
          v = v + (y - v) * 0.5f;
          const bool sp = (v >= 1.0f);
          if (fabsf(v - 1.0f) < MARGINf) fl |= 1u << ((mf * 2 + nf) * 4 + r);
          const unsigned long long m = __ballot(sp);
          if (llo == r) {
            const int oc = oc0 + wr * 32 + mf * 16 + lhi * 4 + r;
            const int nw = ntile * 4 + wc * 2 + nf;
            qrow[(size_t)oc * 16 + nw] = (ushort)((m >> (lhi * 16)) & 0xFFFFull);
          }
          vst[mf][nf][r] = sp ? 0.f : v;
        }
  }

  if (fl) {
    const int cnt = __popc(fl);
    uint base = atomicAdd(flags, (uint)cnt);
#pragma unroll
    for (int mf = 0; mf < 2; ++mf)
#pragma unroll
      for (int nf = 0; nf < 2; ++nf)
#pragma unroll
        for (int r = 0; r < 4; ++r)
          if (fl & (1u << ((mf * 2 + nf) * 4 + r))) {
            const int oc = oc0 + wr * 32 + mf * 16 + lhi * 4 + r;
            const int n = ntile * 64 + wc * 32 + nf * 16 + llo;
            if (base < FLAG_CAP) flags[4 + base] = (((uint)(b << 10) | (uint)oc) << 8) | (uint)n;
            base++;
          }
  }
}

// ---------------------------------------------------------------------------
// K5: exact fixer — recompute flagged (b,oc,n) with the bitwise-exact
// ascending-c f32 chain (identical to the validated round-0 path) and patch
// the packed spike bits atomically.
// ---------------------------------------------------------------------------
__global__ __launch_bounds__(256) void k_fix(
    const uchar* __restrict__ xs,
    const float* __restrict__ qw, const float* __restrict__ kw, const float* __restrict__ vw,
    const float* __restrict__ qga, const float* __restrict__ qbe, const float* __restrict__ qme, const float* __restrict__ qva,
    const float* __restrict__ kga, const float* __restrict__ kbe, const float* __restrict__ kme, const float* __restrict__ kva,
    const float* __restrict__ vga, const float* __restrict__ vbe, const float* __restrict__ vme, const float* __restrict__ vva,
    uint* __restrict__ qp32, const uint* __restrict__ flags) {
#pragma clang fp contract(off)
  const uint cnt = min(flags[0], FLAG_CAP);
  for (uint i = blockIdx.x * 256 + threadIdx.x; i < cnt; i += gridDim.x * 256) {
    const uint e = flags[4 + i];
    const int n = e & 255;
    const int oc = (e >> 8) & 1023;
    const int b = e >> 18;
    const int sel = oc >> 8, ocl = oc & 255;
    const float* W = (sel == 0 ? qw : (sel == 1 ? kw : vw)) + (size_t)ocl * CC;
    const float* G  = sel == 0 ? qga : (sel == 1 ? kga : vga);
    const float* Be = sel == 0 ? qbe : (sel == 1 ? kbe : vbe);
    const float* Mn = sel == 0 ? qme : (sel == 1 ? kme : vme);
    const float* Vr = sel == 0 ? qva : (sel == 1 ? kva : vva);
    const float inv = G[ocl] / sqrtf(Vr[ocl] + EPSf);
    const float mean = Mn[ocl], beta = Be[ocl];
    float v = 0.f;
    for (int t = 0; t < TT; ++t) {
      const uchar* col = xs + ((size_t)(t * BB + b) * CC) * NN + n;
      float acc = 0.f;
      for (int c = 0; c < CC; ++c)
        acc = fmaf(W[c], (float)col[(size_t)c * NN], acc);
      float xm = acc - mean;
      float y = xm * inv;
      y = y + beta;
      float d = (y - v) * 0.5f;
      v = v + d;
      const bool sp = (v >= 1.0f);
      const size_t widx = ((size_t)(t * BB + b) * 768 + oc) * 8 + (n >> 5);
      const uint bit = 1u << (n & 31);
      if (sp) atomicOr(&qp32[widx], bit);
      else atomicAnd(&qp32[widx], ~bit);
      if (sp) v = 0.f;
    }
  }
}

// ---------------------------------------------------------------------------
// K6: attention Q(K^T V)*2scale + LIF, exact integers via popcount on the
// packed spikes; writes proj's B-operand fragments (bf16) directly.
// ---------------------------------------------------------------------------
__global__ __launch_bounds__(256) void k_attn(const ushort* __restrict__ qp,
                                              uchar* __restrict__ attnF) {
  __shared__ uint Qb[32][8], Kb[32][8], Vb[32][8];
  __shared__ int KtV[32][36];
  const int tid = threadIdx.x;
  const int b = blockIdx.x >> 3;
  const int h = blockIdx.x & 7;
  const int ch = tid >> 3, wv = tid & 7;
  const int n = tid;

  float vst[32];
#pragma unroll
  for (int j = 0; j < 32; ++j) vst[j] = 0.f;

  for (int t = 0; t < TT; ++t) {
    __syncthreads();
    const ushort* base = qp + (size_t)(t * BB + b) * 768 * 16;
    Qb[ch][wv] = *reinterpret_cast<const uint*>(base + (size_t)(h * 32 + ch) * 16 + wv * 2);
    Kb[ch][wv] = *reinterpret_cast<const uint*>(base + (size_t)(256 + h * 32 + ch) * 16 + wv * 2);
    Vb[ch][wv] = *reinterpret_cast<const uint*>(base + (size_t)(512 + h * 32 + ch) * 16 + wv * 2);
    __syncthreads();
#pragma unroll
    for (int p = 0; p < 4; ++p) {
      const int ee = tid + p * 256;
      const int ii = ee >> 5, jj = ee & 31;
      int s = 0;
#pragma unroll
      for (int ww = 0; ww < 8; ++ww) s += __popc(Kb[ii][ww] & Vb[jj][ww]);
      KtV[ii][jj] = s;
    }
    __syncthreads();
    int acc[32];
#pragma unroll
    for (int j = 0; j < 32; ++j) acc[j] = 0;
    for (int ii = 0; ii < 32; ++ii) {
      const uint qbit = (Qb[ii][n >> 5] >> (n & 31)) & 1u;
      if (qbit) {
        const int4* row = reinterpret_cast<const int4*>(&KtV[ii][0]);
#pragma unroll
        for (int j4 = 0; j4 < 8; ++j4) {
          int4 kk = row[j4];
          acc[j4 * 4 + 0] += kk.x;
          acc[j4 * 4 + 1] += kk.y;
          acc[j4 * 4 + 2] += kk.z;
          acc[j4 * 4 + 3] += kk.w;
        }
      }
    }
    // scale + LIF -> spike mask
    uint smask = 0;
    {
#pragma clang fp contract(off)
#pragma unroll
      for (int j = 0; j < 32; ++j) {
        float y = (float)acc[j] * MULTf;
        float v = vst[j];
        float d = (y - v) * 0.5f;
        v = v + d;
        const bool sp = (v >= 1.0f);
        if (sp) smask |= 1u << j;
        vst[j] = sp ? 0.f : v;
      }
    }
    // write proj B fragments: chunk (nb=n>>4, ks=h, lane=lhi*16+(n&15)), j=ch
    uint4* dst = reinterpret_cast<uint4*>(attnF) + (size_t)(t * BB + b) * 8192 + (n >> 4) * 512 + h * 64;
#pragma unroll
    for (int lhi = 0; lhi < 4; ++lhi) {
      uint wds[4];
#pragma unroll
      for (int p = 0; p < 4; ++p) {
        const uint b0 = (smask >> (lhi * 8 + p * 2)) & 1u;
        const uint b1 = (smask >> (lhi * 8 + p * 2 + 1)) & 1u;
        wds[p] = (b0 ? 0x3F80u : 0u) | (b1 ? 0x3F800000u : 0u);
      }
      uint4 o; o.x = wds[0]; o.y = wds[1]; o.z = wds[2]; o.w = wds[3];
      dst[lhi * 16 + (n & 15)] = o;
    }
  }
}

// ---------------------------------------------------------------------------
// K7: proj conv (MFMA, 2-split) + BN -> f32 out.
// ---------------------------------------------------------------------------
__global__ __launch_bounds__(256, 2) void k_proj_mfma(
    const uchar* __restrict__ attnF, const uchar* __restrict__ wfp,
    const float* __restrict__ pga, const float* __restrict__ pbe,
    const float* __restrict__ pme, const float* __restrict__ pva,
    float* __restrict__ out) {
  __shared__ short lsB[4][8][64][8];
  const int tid = threadIdx.x;
  const int w = tid >> 6, lane = tid & 63;
  const int lhi = lane >> 4, llo = lane & 15;
  const int wr = w >> 1, wc = w & 1;
  const int oc0 = blockIdx.x * 64;
  const int ntile = blockIdx.y;
  const int tb = blockIdx.z;

  s16x8 wfr[2][2][8];
#pragma unroll
  for (int s = 0; s < 2; ++s)
#pragma unroll
    for (int mf = 0; mf < 2; ++mf) {
      const int ob = blockIdx.x * 4 + wr * 2 + mf;
#pragma unroll
      for (int ks = 0; ks < 8; ++ks)
        wfr[s][mf][ks] = *reinterpret_cast<const s16x8*>(
            wfp + ((((size_t)s * 16 + ob) * 8 + ks) * 64 + lane) * 16);
    }

  float inv8[2][4], mean8[2][4], beta8[2][4];
#pragma unroll
  for (int mf = 0; mf < 2; ++mf)
#pragma unroll
    for (int r = 0; r < 4; ++r) {
      const int ocb = oc0 + wr * 32 + mf * 16 + lhi * 4 + r;
      inv8[mf][r] = pga[ocb] / sqrtf(pva[ocb] + EPSf);
      mean8[mf][r] = pme[ocb];
      beta8[mf][r] = pbe[ocb];
    }

  const uchar* src = attnF + (((size_t)tb * 16 + ntile * 4) * 8192);
#pragma unroll
  for (int k2 = 0; k2 < 8; ++k2) {
    const int chunk = w * 8 + k2;
    gload_lds16(src + (size_t)chunk * 1024 + lane * 16,
                reinterpret_cast<char*>(&lsB[0][0][0][0]) + chunk * 1024);
  }
  __syncthreads();

  f32x4 acc[2][2];
#pragma unroll
  for (int mf = 0; mf < 2; ++mf)
#pragma unroll
    for (int nf = 0; nf < 2; ++nf) acc[mf][nf] = (f32x4){0.f, 0.f, 0.f, 0.f};

#pragma unroll
  for (int ks = 0; ks < 8; ++ks) {
    s16x8 b0 = *reinterpret_cast<const s16x8*>(&lsB[wc * 2][ks][lane][0]);
    s16x8 b1 = *reinterpret_cast<const s16x8*>(&lsB[wc * 2 + 1][ks][lane][0]);
#pragma unroll
    for (int s = 0; s < 2; ++s)
#pragma unroll
      for (int mf = 0; mf < 2; ++mf) {
        acc[mf][0] = __builtin_amdgcn_mfma_f32_16x16x32_bf16(wfr[s][mf][ks], b0, acc[mf][0], 0, 0, 0);
        acc[mf][1] = __builtin_amdgcn_mfma_f32_16x16x32_bf16(wfr[s][mf][ks], b1, acc[mf][1], 0, 0, 0);
      }
  }

#pragma unroll
  for (int mf = 0; mf < 2; ++mf)
#pragma unroll
    for (int nf = 0; nf < 2; ++nf)
#pragma unroll
      for (int r = 0; r < 4; ++r) {
        const int oc = oc0 + wr * 32 + mf * 16 + lhi * 4 + r;
        const int nn = ntile * 64 + wc * 32 + nf * 16 + llo;
        float y = (acc[mf][nf][r] - mean8[mf][r]) * inv8[mf][r] + beta8[mf][r];
        out[((size_t)tb * CC + oc) * NN + nn] = y;
      }
}

// ---------------------------------------------------------------------------
extern "C" void kernel_launch(void* const* d_in, const int* in_sizes, int n_in,
                              void* d_out, int out_size, void* d_ws, size_t ws_size,
                              hipStream_t stream) {
  const float* x = (const float*)d_in[0];
  const float* q_w = (const float*)d_in[1];
  const float* q_g = (const float*)d_in[2];
  const float* q_b = (const float*)d_in[3];
  const float* q_m = (const float*)d_in[4];
  const float* q_v = (const float*)d_in[5];
  const float* k_w = (const float*)d_in[6];
  const float* k_g = (const float*)d_in[7];
  const float* k_b = (const float*)d_in[8];
  const float* k_m = (const float*)d_in[9];
  const float* k_v = (const float*)d_in[10];
  const float* v_w = (const float*)d_in[11];
  const float* v_g = (const float*)d_in[12];
  const float* v_b = (const float*)d_in[13];
  const float* v_m = (const float*)d_in[14];
  const float* v_v = (const float*)d_in[15];
  const float* p_w = (const float*)d_in[16];
  const float* p_g = (const float*)d_in[17];
  const float* p_b = (const float*)d_in[18];
  const float* p_m = (const float*)d_in[19];
  const float* p_v = (const float*)d_in[20];

  uchar* ws = (uchar*)d_ws;
  uchar* xs   = ws;                         // 8 MiB  [t][b][c][n] u8
  ushort* qp  = (ushort*)(ws + 8388608);    // 3 MiB  packed spikes [t][b][768][16]
  uchar* xsF  = ws + 11534336;              // 16 MiB frags (shared with attnF)
  uchar* wfq  = ws + 28311552;              // 768 KiB
  uchar* wfp  = ws + 29097984;              // 256 KiB
  uint* flags = (uint*)(ws + 29360128);     // 16B counter + list (2 MiB)

  hipMemsetAsync(flags, 0, 16, stream);

  k_prep_w<<<dim3(128), 256, 0, stream>>>(q_w, k_w, v_w, p_w, wfq, wfp);
  k_lif_x<<<dim3(2048), 256, 0, stream>>>(x, xs);
  k_fragx<<<dim3(256), 256, 0, stream>>>(xs, xsF);
  k_qkv_mfma<<<dim3(12, 4, 32), 256, 0, stream>>>(xsF, wfq,
                                                  q_g, q_b, q_m, q_v,
                                                  k_g, k_b, k_m, k_v,
                                                  v_g, v_b, v_m, v_v,
                                                  qp, flags);
  k_fix<<<dim3(128), 256, 0, stream>>>(xs, q_w, k_w, v_w,
                                       q_g, q_b, q_m, q_v,
                                       k_g, k_b, k_m, k_v,
                                       v_g, v_b, v_m, v_v,
                                       (uint*)qp, flags);
  k_attn<<<dim3(256), 256, 0, stream>>>(qp, xsF /* attnF shares region */);
  k_proj_mfma<<<dim3(4, 4, 128), 256, 0, stream>>>(xsF, wfp, p_g, p_b, p_m, p_v,
                                                   (float*)d_out);
}

// Round 3
// 151.253 us; speedup vs baseline: 1.7015x; 1.1152x over previous
//
#include <hip/hip_runtime.h>

#define TT 4
#define BB 32
#define CC 256
#define NN 256
#define EPSf 1e-5f
#define MULTf 0.35355339059327373f
#define MARGINf 3e-3f
#define FLAG_CAP 524288u

typedef __attribute__((ext_vector_type(8))) short s16x8;
typedef __attribute__((ext_vector_type(4))) float f32x4;
typedef unsigned char uchar;
typedef unsigned int uint;
typedef unsigned short ushort;

// bf16 round-to-nearest-even
__device__ __forceinline__ ushort f2bf_rn(float f) {
  uint u = __float_as_uint(f);
  u = (u + 0x7FFFu + ((u >> 16) & 1u)) >> 16;
  return (ushort)u;
}
__device__ __forceinline__ float bf2f(ushort b) {
  return __uint_as_float(((uint)b) << 16);
}

__device__ __forceinline__ void gload_lds16(const void* g, void* l) {
  __builtin_amdgcn_global_load_lds(
      (const __attribute__((address_space(1))) uint*)g,
      (__attribute__((address_space(3))) uint*)l, 16, 0, 0);
}

// ---------------------------------------------------------------------------
// K1: xs = lif(x) fused with fragment layout: writes bf16 spike fragments
//   xsF chunk(16B) at uint4 idx ((t*BB+b)*16 + n/16)*512 + ks*64 + oct*16 + n%16
//   holding bf16 spikes for c = ks*32 + oct*8 + {0..7} at token n.
// LIF bitwise-exact (halving exact, contract off).
// Thread = (b, n, c-octet); block = 64n x 4oct; grid = (4 ntiles, 8 ks, 32 b).
// ---------------------------------------------------------------------------
__global__ __launch_bounds__(256) void k_lif_frag(const float* __restrict__ x,
                                                  uchar* __restrict__ xsF) {
#pragma clang fp contract(off)
  const int tid = threadIdx.x;
  const int nt = blockIdx.x;   // n-tile
  const int ks = blockIdx.y;   // 0..7
  const int b = blockIdx.z;    // 0..31
  const int nl = tid & 63;
  const int oct = tid >> 6;    // 0..3
  const int n = nt * 64 + nl;
  const int c0 = ks * 32 + oct * 8;
  const size_t stride = (size_t)BB * CC * NN;
  const float* xb = x + ((size_t)b * CC + c0) * NN + n;

  float v[8];
#pragma unroll
  for (int j = 0; j < 8; ++j) v[j] = 0.f;

#pragma unroll
  for (int t = 0; t < TT; ++t) {
    ushort sp[8];
#pragma unroll
    for (int j = 0; j < 8; ++j) {
      float xt = xb[t * stride + (size_t)j * NN];
      float d = (xt - v[j]) * 0.5f;
      v[j] = v[j] + d;
      bool s = (v[j] >= 1.0f);
      sp[j] = s ? (ushort)0x3F80 : (ushort)0;
      if (s) v[j] = 0.f;
    }
    uint4* dst = reinterpret_cast<uint4*>(xsF) +
                 (((size_t)(t * BB + b) * 16 + (n >> 4)) * 512 + ks * 64 + oct * 16 + (n & 15));
    uint4 o;
    o.x = (uint)sp[0] | ((uint)sp[1] << 16);
    o.y = (uint)sp[2] | ((uint)sp[3] << 16);
    o.z = (uint)sp[4] | ((uint)sp[5] << 16);
    o.w = (uint)sp[6] | ((uint)sp[7] << 16);
    *dst = o;
  }
}

// ---------------------------------------------------------------------------
// K2: weight prep — 2-way bf16 split, MFMA-fragment-ready layout.
// ---------------------------------------------------------------------------
__global__ __launch_bounds__(256) void k_prep_w(
    const float* __restrict__ qw, const float* __restrict__ kw,
    const float* __restrict__ vw, const float* __restrict__ pw,
    uchar* __restrict__ wfq, uchar* __restrict__ wfp) {
  const int gid = blockIdx.x * 256 + threadIdx.x;  // 0..32767
  const int ob2 = gid >> 9;                        // 0..63
  const int e = gid & 511;
  const int ks = e >> 6, l = e & 63;
  const float* W;
  uchar* outb;
  int ob_out, nob;
  if (ob2 < 48) {
    const int sel = ob2 >> 4;
    W = sel == 0 ? qw : (sel == 1 ? kw : vw);
    W += ((size_t)((ob2 & 15) * 16 + (l & 15))) * CC;
    outb = wfq; ob_out = ob2; nob = 48;
  } else {
    W = pw + ((size_t)((ob2 - 48) * 16 + (l & 15))) * CC;
    outb = wfp; ob_out = ob2 - 48; nob = 16;
  }
  const int c0 = ks * 32 + (l >> 4) * 8;
  float wv[8];
  *reinterpret_cast<float4*>(&wv[0]) = *reinterpret_cast<const float4*>(W + c0);
  *reinterpret_cast<float4*>(&wv[4]) = *reinterpret_cast<const float4*>(W + c0 + 4);
  ushort hi[8], lo[8];
#pragma unroll
  for (int j = 0; j < 8; ++j) {
    hi[j] = f2bf_rn(wv[j]);
    lo[j] = f2bf_rn(wv[j] - bf2f(hi[j]));
  }
  const size_t base = (((size_t)ob_out * 8 + ks) * 64 + l) * 16;
  const size_t sstr = (size_t)nob * 8 * 64 * 16;
  *reinterpret_cast<uint4*>(outb + base) = *reinterpret_cast<const uint4*>(hi);
  *reinterpret_cast<uint4*>(outb + sstr + base) = *reinterpret_cast<const uint4*>(lo);
}

// ---------------------------------------------------------------------------
// K4: fused q/k/v conv (MFMA, 2-split bf16) + BN + LIF -> bit-packed spikes
//     + near-threshold flags for the exact fixer.
// ---------------------------------------------------------------------------
__global__ __launch_bounds__(256, 2) void k_qkv_mfma(
    const uchar* __restrict__ xsF, const uchar* __restrict__ wfq,
    const float* __restrict__ qga, const float* __restrict__ qbe, const float* __restrict__ qme, const float* __restrict__ qva,
    const float* __restrict__ kga, const float* __restrict__ kbe, const float* __restrict__ kme, const float* __restrict__ kva,
    const float* __restrict__ vga, const float* __restrict__ vbe, const float* __restrict__ vme, const float* __restrict__ vva,
    ushort* __restrict__ qp, uint* __restrict__ flags) {
  __shared__ short lsB[4][8][64][8];  // 32KB
  const int tid = threadIdx.x;
  const int w = tid >> 6, lane = tid & 63;
  const int lhi = lane >> 4, llo = lane & 15;
  const int wr = w >> 1, wc = w & 1;
  const int oc0 = blockIdx.x * 64;
  const int ntile = blockIdx.y;
  const int b = blockIdx.z;
  const int sel = oc0 >> 8;
  const float* G  = sel == 0 ? qga : (sel == 1 ? kga : vga);
  const float* Be = sel == 0 ? qbe : (sel == 1 ? kbe : vbe);
  const float* Mn = sel == 0 ? qme : (sel == 1 ? kme : vme);
  const float* Vr = sel == 0 ? qva : (sel == 1 ? kva : vva);

  s16x8 wfr[2][2][8];
#pragma unroll
  for (int s = 0; s < 2; ++s)
#pragma unroll
    for (int mf = 0; mf < 2; ++mf) {
      const int ob = blockIdx.x * 4 + wr * 2 + mf;
#pragma unroll
      for (int ks = 0; ks < 8; ++ks)
        wfr[s][mf][ks] = *reinterpret_cast<const s16x8*>(
            wfq + ((((size_t)s * 48 + ob) * 8 + ks) * 64 + lane) * 16);
    }

  float inv8[2][4], mean8[2][4], beta8[2][4];
#pragma unroll
  for (int mf = 0; mf < 2; ++mf)
#pragma unroll
    for (int r = 0; r < 4; ++r) {
      const int ocb = (oc0 & 255) + wr * 32 + mf * 16 + lhi * 4 + r;
      inv8[mf][r] = G[ocb] / sqrtf(Vr[ocb] + EPSf);
      mean8[mf][r] = Mn[ocb];
      beta8[mf][r] = Be[ocb];
    }

  float vst[2][2][4];
#pragma unroll
  for (int mf = 0; mf < 2; ++mf)
#pragma unroll
    for (int nf = 0; nf < 2; ++nf)
#pragma unroll
      for (int r = 0; r < 4; ++r) vst[mf][nf][r] = 0.f;
  uint fl = 0;

  for (int t = 0; t < TT; ++t) {
    __syncthreads();
    const uchar* src = xsF + (((size_t)(t * BB + b) * 16 + ntile * 4) * 8192);
#pragma unroll
    for (int k2 = 0; k2 < 8; ++k2) {
      const int chunk = w * 8 + k2;
      gload_lds16(src + (size_t)chunk * 1024 + lane * 16,
                  reinterpret_cast<char*>(&lsB[0][0][0][0]) + chunk * 1024);
    }
    __syncthreads();

    f32x4 acc[2][2];
#pragma unroll
    for (int mf = 0; mf < 2; ++mf)
#pragma unroll
      for (int nf = 0; nf < 2; ++nf) acc[mf][nf] = (f32x4){0.f, 0.f, 0.f, 0.f};

#pragma unroll
    for (int ks = 0; ks < 8; ++ks) {
      s16x8 b0 = *reinterpret_cast<const s16x8*>(&lsB[wc * 2][ks][lane][0]);
      s16x8 b1 = *reinterpret_cast<const s16x8*>(&lsB[wc * 2 + 1][ks][lane][0]);
#pragma unroll
      for (int s = 0; s < 2; ++s)
#pragma unroll
        for (int mf = 0; mf < 2; ++mf) {
          acc[mf][0] = __builtin_amdgcn_mfma_f32_16x16x32_bf16(wfr[s][mf][ks], b0, acc[mf][0], 0, 0, 0);
          acc[mf][1] = __builtin_amdgcn_mfma_f32_16x16x32_bf16(wfr[s][mf][ks], b1, acc[mf][1], 0, 0, 0);
        }
    }

    ushort* qrow = qp + (size_t)(t * BB + b) * 768 * 16;
#pragma unroll
    for (int mf = 0; mf < 2; ++mf)
#pragma unroll
      for (int nf = 0; nf < 2; ++nf)
#pragma unroll
        for (int r = 0; r < 4; ++r) {
          float y = (acc[mf][nf][r] - mean8[mf][r]) * inv8[mf][r] + beta8[mf][r];
          float v = vst[mf][nf][r];
          v = v + (y - v) * 0.5f;
          const bool sp = (v >= 1.0f);
          if (fabsf(v - 1.0f) < MARGINf) fl |= 1u << ((mf * 2 + nf) * 4 + r);
          const unsigned long long m = __ballot(sp);
          if (llo == r) {
            const int oc = oc0 + wr * 32 + mf * 16 + lhi * 4 + r;
            const int nw = ntile * 4 + wc * 2 + nf;
            qrow[(size_t)oc * 16 + nw] = (ushort)((m >> (lhi * 16)) & 0xFFFFull);
          }
          vst[mf][nf][r] = sp ? 0.f : v;
        }
  }

  if (fl) {
    const int cnt = __popc(fl);
    uint base = atomicAdd(flags, (uint)cnt);
#pragma unroll
    for (int mf = 0; mf < 2; ++mf)
#pragma unroll
      for (int nf = 0; nf < 2; ++nf)
#pragma unroll
        for (int r = 0; r < 4; ++r)
          if (fl & (1u << ((mf * 2 + nf) * 4 + r))) {
            const int oc = oc0 + wr * 32 + mf * 16 + lhi * 4 + r;
            const int n = ntile * 64 + wc * 32 + nf * 16 + llo;
            if (base < FLAG_CAP) flags[4 + base] = (((uint)(b << 10) | (uint)oc) << 8) | (uint)n;
            base++;
          }
  }
}

// ---------------------------------------------------------------------------
// K5: exact fixer, lane-parallel. One flagged element per lane; 4 independent
// per-t add chains (ILP) over xsF spike chunks + original f32 weight rows.
// acc += spike ? w : 0 is bitwise-identical to the ascending-c reference sum.
// ---------------------------------------------------------------------------
__global__ __launch_bounds__(256) void k_fix(
    const uchar* __restrict__ xsF,
    const float* __restrict__ qw, const float* __restrict__ kw, const float* __restrict__ vw,
    const float* __restrict__ qga, const float* __restrict__ qbe, const float* __restrict__ qme, const float* __restrict__ qva,
    const float* __restrict__ kga, const float* __restrict__ kbe, const float* __restrict__ kme, const float* __restrict__ kva,
    const float* __restrict__ vga, const float* __restrict__ vbe, const float* __restrict__ vme, const float* __restrict__ vva,
    uint* __restrict__ qp32, const uint* __restrict__ flags) {
#pragma clang fp contract(off)
  const uint cnt = min(flags[0], FLAG_CAP);
  for (uint i = blockIdx.x * 256 + threadIdx.x; i < cnt; i += gridDim.x * 256) {
    const uint e = flags[4 + i];
    const int n = e & 255;
    const int oc = (e >> 8) & 1023;
    const int b = e >> 18;
    const int sel = oc >> 8, ocl = oc & 255;
    const float* W = (sel == 0 ? qw : (sel == 1 ? kw : vw)) + (size_t)ocl * CC;
    const float* G  = sel == 0 ? qga : (sel == 1 ? kga : vga);
    const float* Be = sel == 0 ? qbe : (sel == 1 ? kbe : vbe);
    const float* Mn = sel == 0 ? qme : (sel == 1 ? kme : vme);
    const float* Vr = sel == 0 ? qva : (sel == 1 ? kva : vva);

    const uint4* chunkbase = reinterpret_cast<const uint4*>(xsF) +
                             ((size_t)b * 16 + (n >> 4)) * 512 + (n & 15);

    float acc0 = 0.f, acc1 = 0.f, acc2 = 0.f, acc3 = 0.f;
#pragma unroll
    for (int ks = 0; ks < 8; ++ks) {
#pragma unroll
      for (int oct = 0; oct < 4; ++oct) {
        float wv[8];
        *reinterpret_cast<float4*>(&wv[0]) =
            *reinterpret_cast<const float4*>(W + ks * 32 + oct * 8);
        *reinterpret_cast<float4*>(&wv[4]) =
            *reinterpret_cast<const float4*>(W + ks * 32 + oct * 8 + 4);
        uint4 s0 = chunkbase[(size_t)(0 * BB) * 16 * 512 + ks * 64 + oct * 16];
        uint4 s1 = chunkbase[(size_t)(1 * BB) * 16 * 512 + ks * 64 + oct * 16];
        uint4 s2 = chunkbase[(size_t)(2 * BB) * 16 * 512 + ks * 64 + oct * 16];
        uint4 s3 = chunkbase[(size_t)(3 * BB) * 16 * 512 + ks * 64 + oct * 16];
        const ushort* p0 = reinterpret_cast<const ushort*>(&s0);
        const ushort* p1 = reinterpret_cast<const ushort*>(&s1);
        const ushort* p2 = reinterpret_cast<const ushort*>(&s2);
        const ushort* p3 = reinterpret_cast<const ushort*>(&s3);
#pragma unroll
        for (int j = 0; j < 8; ++j) {
          acc0 = acc0 + (p0[j] ? wv[j] : 0.f);
          acc1 = acc1 + (p1[j] ? wv[j] : 0.f);
          acc2 = acc2 + (p2[j] ? wv[j] : 0.f);
          acc3 = acc3 + (p3[j] ? wv[j] : 0.f);
        }
      }
    }
    float accs[4] = {acc0, acc1, acc2, acc3};

    const float inv = G[ocl] / sqrtf(Vr[ocl] + EPSf);
    const float mean = Mn[ocl], beta = Be[ocl];
    float v = 0.f;
#pragma unroll
    for (int t = 0; t < TT; ++t) {
      float xm = accs[t] - mean;
      float y = xm * inv;
      y = y + beta;
      float d = (y - v) * 0.5f;
      v = v + d;
      const bool sp = (v >= 1.0f);
      const size_t widx = ((size_t)(t * BB + b) * 768 + oc) * 8 + (n >> 5);
      const uint bit = 1u << (n & 31);
      if (sp) atomicOr(&qp32[widx], bit);
      else atomicAnd(&qp32[widx], ~bit);
      if (sp) v = 0.f;
    }
  }
}

// ---------------------------------------------------------------------------
// K6: attention Q(K^T V)*2scale + LIF via popcount; writes proj B-fragments.
// ---------------------------------------------------------------------------
__global__ __launch_bounds__(256) void k_attn(const ushort* __restrict__ qp,
                                              uchar* __restrict__ attnF) {
  __shared__ uint Qb[32][8], Kb[32][8], Vb[32][8];
  __shared__ int KtV[32][36];
  const int tid = threadIdx.x;
  const int b = blockIdx.x >> 3;
  const int h = blockIdx.x & 7;
  const int ch = tid >> 3, wv = tid & 7;
  const int n = tid;

  float vst[32];
#pragma unroll
  for (int j = 0; j < 32; ++j) vst[j] = 0.f;

  for (int t = 0; t < TT; ++t) {
    __syncthreads();
    const ushort* base = qp + (size_t)(t * BB + b) * 768 * 16;
    Qb[ch][wv] = *reinterpret_cast<const uint*>(base + (size_t)(h * 32 + ch) * 16 + wv * 2);
    Kb[ch][wv] = *reinterpret_cast<const uint*>(base + (size_t)(256 + h * 32 + ch) * 16 + wv * 2);
    Vb[ch][wv] = *reinterpret_cast<const uint*>(base + (size_t)(512 + h * 32 + ch) * 16 + wv * 2);
    __syncthreads();
#pragma unroll
    for (int p = 0; p < 4; ++p) {
      const int ee = tid + p * 256;
      const int ii = ee >> 5, jj = ee & 31;
      int s = 0;
#pragma unroll
      for (int ww = 0; ww < 8; ++ww) s += __popc(Kb[ii][ww] & Vb[jj][ww]);
      KtV[ii][jj] = s;
    }
    __syncthreads();
    int acc[32];
#pragma unroll
    for (int j = 0; j < 32; ++j) acc[j] = 0;
    for (int ii = 0; ii < 32; ++ii) {
      const uint qbit = (Qb[ii][n >> 5] >> (n & 31)) & 1u;
      if (qbit) {
        const int4* row = reinterpret_cast<const int4*>(&KtV[ii][0]);
#pragma unroll
        for (int j4 = 0; j4 < 8; ++j4) {
          int4 kk = row[j4];
          acc[j4 * 4 + 0] += kk.x;
          acc[j4 * 4 + 1] += kk.y;
          acc[j4 * 4 + 2] += kk.z;
          acc[j4 * 4 + 3] += kk.w;
        }
      }
    }
    uint smask = 0;
    {
#pragma clang fp contract(off)
#pragma unroll
      for (int j = 0; j < 32; ++j) {
        float y = (float)acc[j] * MULTf;
        float v = vst[j];
        float d = (y - v) * 0.5f;
        v = v + d;
        const bool sp = (v >= 1.0f);
        if (sp) smask |= 1u << j;
        vst[j] = sp ? 0.f : v;
      }
    }
    uint4* dst = reinterpret_cast<uint4*>(attnF) + (size_t)(t * BB + b) * 8192 + (n >> 4) * 512 + h * 64;
#pragma unroll
    for (int lhi = 0; lhi < 4; ++lhi) {
      uint wds[4];
#pragma unroll
      for (int p = 0; p < 4; ++p) {
        const uint b0 = (smask >> (lhi * 8 + p * 2)) & 1u;
        const uint b1 = (smask >> (lhi * 8 + p * 2 + 1)) & 1u;
        wds[p] = (b0 ? 0x3F80u : 0u) | (b1 ? 0x3F800000u : 0u);
      }
      uint4 o; o.x = wds[0]; o.y = wds[1]; o.z = wds[2]; o.w = wds[3];
      dst[lhi * 16 + (n & 15)] = o;
    }
  }
}

// ---------------------------------------------------------------------------
// K7: proj conv (MFMA, 2-split) + BN -> f32 out.
// ---------------------------------------------------------------------------
__global__ __launch_bounds__(256, 2) void k_proj_mfma(
    const uchar* __restrict__ attnF, const uchar* __restrict__ wfp,
    const float* __restrict__ pga, const float* __restrict__ pbe,
    const float* __restrict__ pme, const float* __restrict__ pva,
    float* __restrict__ out) {
  __shared__ short lsB[4][8][64][8];
  const int tid = threadIdx.x;
  const int w = tid >> 6, lane = tid & 63;
  const int lhi = lane >> 4, llo = lane & 15;
  const int wr = w >> 1, wc = w & 1;
  const int oc0 = blockIdx.x * 64;
  const int ntile = blockIdx.y;
  const int tb = blockIdx.z;

  s16x8 wfr[2][2][8];
#pragma unroll
  for (int s = 0; s < 2; ++s)
#pragma unroll
    for (int mf = 0; mf < 2; ++mf) {
      const int ob = blockIdx.x * 4 + wr * 2 + mf;
#pragma unroll
      for (int ks = 0; ks < 8; ++ks)
        wfr[s][mf][ks] = *reinterpret_cast<const s16x8*>(
            wfp + ((((size_t)s * 16 + ob) * 8 + ks) * 64 + lane) * 16);
    }

  float inv8[2][4], mean8[2][4], beta8[2][4];
#pragma unroll
  for (int mf = 0; mf < 2; ++mf)
#pragma unroll
    for (int r = 0; r < 4; ++r) {
      const int ocb = oc0 + wr * 32 + mf * 16 + lhi * 4 + r;
      inv8[mf][r] = pga[ocb] / sqrtf(pva[ocb] + EPSf);
      mean8[mf][r] = pme[ocb];
      beta8[mf][r] = pbe[ocb];
    }

  const uchar* src = attnF + (((size_t)tb * 16 + ntile * 4) * 8192);
#pragma unroll
  for (int k2 = 0; k2 < 8; ++k2) {
    const int chunk = w * 8 + k2;
    gload_lds16(src + (size_t)chunk * 1024 + lane * 16,
                reinterpret_cast<char*>(&lsB[0][0][0][0]) + chunk * 1024);
  }
  __syncthreads();

  f32x4 acc[2][2];
#pragma unroll
  for (int mf = 0; mf < 2; ++mf)
#pragma unroll
    for (int nf = 0; nf < 2; ++nf) acc[mf][nf] = (f32x4){0.f, 0.f, 0.f, 0.f};

#pragma unroll
  for (int ks = 0; ks < 8; ++ks) {
    s16x8 b0 = *reinterpret_cast<const s16x8*>(&lsB[wc * 2][ks][lane][0]);
    s16x8 b1 = *reinterpret_cast<const s16x8*>(&lsB[wc * 2 + 1][ks][lane][0]);
#pragma unroll
    for (int s = 0; s < 2; ++s)
#pragma unroll
      for (int mf = 0; mf < 2; ++mf) {
        acc[mf][0] = __builtin_amdgcn_mfma_f32_16x16x32_bf16(wfr[s][mf][ks], b0, acc[mf][0], 0, 0, 0);
        acc[mf][1] = __builtin_amdgcn_mfma_f32_16x16x32_bf16(wfr[s][mf][ks], b1, acc[mf][1], 0, 0, 0);
      }
  }

#pragma unroll
  for (int mf = 0; mf < 2; ++mf)
#pragma unroll
    for (int nf = 0; nf < 2; ++nf)
#pragma unroll
      for (int r = 0; r < 4; ++r) {
        const int oc = oc0 + wr * 32 + mf * 16 + lhi * 4 + r;
        const int nn = ntile * 64 + wc * 32 + nf * 16 + llo;
        float y = (acc[mf][nf][r] - mean8[mf][r]) * inv8[mf][r] + beta8[mf][r];
        out[((size_t)tb * CC + oc) * NN + nn] = y;
      }
}

// ---------------------------------------------------------------------------
extern "C" void kernel_launch(void* const* d_in, const int* in_sizes, int n_in,
                              void* d_out, int out_size, void* d_ws, size_t ws_size,
                              hipStream_t stream) {
  const float* x = (const float*)d_in[0];
  const float* q_w = (const float*)d_in[1];
  const float* q_g = (const float*)d_in[2];
  const float* q_b = (const float*)d_in[3];
  const float* q_m = (const float*)d_in[4];
  const float* q_v = (const float*)d_in[5];
  const float* k_w = (const float*)d_in[6];
  const float* k_g = (const float*)d_in[7];
  const float* k_b = (const float*)d_in[8];
  const float* k_m = (const float*)d_in[9];
  const float* k_v = (const float*)d_in[10];
  const float* v_w = (const float*)d_in[11];
  const float* v_g = (const float*)d_in[12];
  const float* v_b = (const float*)d_in[13];
  const float* v_m = (const float*)d_in[14];
  const float* v_v = (const float*)d_in[15];
  const float* p_w = (const float*)d_in[16];
  const float* p_g = (const float*)d_in[17];
  const float* p_b = (const float*)d_in[18];
  const float* p_m = (const float*)d_in[19];
  const float* p_v = (const float*)d_in[20];

  uchar* ws = (uchar*)d_ws;
  uchar* xsF  = ws;                         // 16 MiB frags (reused as attnF)
  ushort* qp  = (ushort*)(ws + 16777216);   // 3 MiB packed spikes
  uchar* wfq  = ws + 19922944;              // 768 KiB
  uchar* wfp  = ws + 20709376;              // 256 KiB
  uint* flags = (uint*)(ws + 20971520);     // 16 B counter + list (2 MiB)

  hipMemsetAsync(flags, 0, 16, stream);

  k_prep_w<<<dim3(128), 256, 0, stream>>>(q_w, k_w, v_w, p_w, wfq, wfp);
  k_lif_frag<<<dim3(4, 8, 32), 256, 0, stream>>>(x, xsF);
  k_qkv_mfma<<<dim3(12, 4, 32), 256, 0, stream>>>(xsF, wfq,
                                                  q_g, q_b, q_m, q_v,
                                                  k_g, k_b, k_m, k_v,
                                                  v_g, v_b, v_m, v_v,
                                                  qp, flags);
  k_fix<<<dim3(256), 256, 0, stream>>>(xsF, q_w, k_w, v_w,
                                       q_g, q_b, q_m, q_v,
                                       k_g, k_b, k_m, k_v,
                                       v_g, v_b, v_m, v_v,
                                       (uint*)qp, flags);
  k_attn<<<dim3(256), 256, 0, stream>>>(qp, xsF /* attnF shares region */);
  k_proj_mfma<<<dim3(4, 4, 128), 256, 0, stream>>>(xsF, wfp, p_g, p_b, p_m, p_v,
                                                   (float*)d_out);
}

// Round 4
// 113.542 us; speedup vs baseline: 2.2667x; 1.3321x over previous
//
#include <hip/hip_runtime.h>

#define TT 4
#define BB 32
#define CC 256
#define NN 256
#define EPSf 1e-5f
#define MULTf 0.35355339059327373f
#define MARGINf 1e-3f
#define FLAG_CAP 524288u

typedef __attribute__((ext_vector_type(8))) short s16x8;
typedef __attribute__((ext_vector_type(4))) float f32x4;
typedef unsigned char uchar;
typedef unsigned int uint;
typedef unsigned short ushort;

// bf16 round-to-nearest-even
__device__ __forceinline__ ushort f2bf_rn(float f) {
  uint u = __float_as_uint(f);
  u = (u + 0x7FFFu + ((u >> 16) & 1u)) >> 16;
  return (ushort)u;
}
__device__ __forceinline__ float bf2f(ushort b) {
  return __uint_as_float(((uint)b) << 16);
}

__device__ __forceinline__ void gload_lds16(const void* g, void* l) {
  __builtin_amdgcn_global_load_lds(
      (const __attribute__((address_space(1))) uint*)g,
      (__attribute__((address_space(3))) uint*)l, 16, 0, 0);
}

// ---------------------------------------------------------------------------
// K1: xs = lif(x) fused with fragment layout (bf16 MFMA B-operand chunks)
//     + bit-packed spikes xsP (32 B per (t,b,n): bit c of byte c>>3).
// LIF bitwise-exact (halving exact, contract off).
// ---------------------------------------------------------------------------
__global__ __launch_bounds__(256) void k_lif_frag(const float* __restrict__ x,
                                                  uchar* __restrict__ xsF,
                                                  uchar* __restrict__ xsP) {
#pragma clang fp contract(off)
  const int tid = threadIdx.x;
  const int nt = blockIdx.x;   // n-tile
  const int ks = blockIdx.y;   // 0..7
  const int b = blockIdx.z;    // 0..31
  const int nl = tid & 63;
  const int oct = tid >> 6;    // 0..3
  const int n = nt * 64 + nl;
  const int c0 = ks * 32 + oct * 8;
  const size_t stride = (size_t)BB * CC * NN;
  const float* xb = x + ((size_t)b * CC + c0) * NN + n;

  float v[8];
#pragma unroll
  for (int j = 0; j < 8; ++j) v[j] = 0.f;

#pragma unroll
  for (int t = 0; t < TT; ++t) {
    ushort sp[8];
    uint pm = 0;
#pragma unroll
    for (int j = 0; j < 8; ++j) {
      float xt = xb[t * stride + (size_t)j * NN];
      float d = (xt - v[j]) * 0.5f;
      v[j] = v[j] + d;
      bool s = (v[j] >= 1.0f);
      sp[j] = s ? (ushort)0x3F80 : (ushort)0;
      if (s) { v[j] = 0.f; pm |= 1u << j; }
    }
    uint4* dst = reinterpret_cast<uint4*>(xsF) +
                 (((size_t)(t * BB + b) * 16 + (n >> 4)) * 512 + ks * 64 + oct * 16 + (n & 15));
    uint4 o;
    o.x = (uint)sp[0] | ((uint)sp[1] << 16);
    o.y = (uint)sp[2] | ((uint)sp[3] << 16);
    o.z = (uint)sp[4] | ((uint)sp[5] << 16);
    o.w = (uint)sp[6] | ((uint)sp[7] << 16);
    *dst = o;
    xsP[(((size_t)(t * BB + b) * NN + n) << 5) + ks * 4 + oct] = (uchar)pm;
  }
}

// ---------------------------------------------------------------------------
// K2: weight prep — 2-way bf16 split, MFMA-fragment-ready layout.
// ---------------------------------------------------------------------------
__global__ __launch_bounds__(256) void k_prep_w(
    const float* __restrict__ qw, const float* __restrict__ kw,
    const float* __restrict__ vw, const float* __restrict__ pw,
    uchar* __restrict__ wfq, uchar* __restrict__ wfp) {
  const int gid = blockIdx.x * 256 + threadIdx.x;  // 0..32767
  const int ob2 = gid >> 9;                        // 0..63
  const int e = gid & 511;
  const int ks = e >> 6, l = e & 63;
  const float* W;
  uchar* outb;
  int ob_out, nob;
  if (ob2 < 48) {
    const int sel = ob2 >> 4;
    W = sel == 0 ? qw : (sel == 1 ? kw : vw);
    W += ((size_t)((ob2 & 15) * 16 + (l & 15))) * CC;
    outb = wfq; ob_out = ob2; nob = 48;
  } else {
    W = pw + ((size_t)((ob2 - 48) * 16 + (l & 15))) * CC;
    outb = wfp; ob_out = ob2 - 48; nob = 16;
  }
  const int c0 = ks * 32 + (l >> 4) * 8;
  float wv[8];
  *reinterpret_cast<float4*>(&wv[0]) = *reinterpret_cast<const float4*>(W + c0);
  *reinterpret_cast<float4*>(&wv[4]) = *reinterpret_cast<const float4*>(W + c0 + 4);
  ushort hi[8], lo[8];
#pragma unroll
  for (int j = 0; j < 8; ++j) {
    hi[j] = f2bf_rn(wv[j]);
    lo[j] = f2bf_rn(wv[j] - bf2f(hi[j]));
  }
  const size_t base = (((size_t)ob_out * 8 + ks) * 64 + l) * 16;
  const size_t sstr = (size_t)nob * 8 * 64 * 16;
  *reinterpret_cast<uint4*>(outb + base) = *reinterpret_cast<const uint4*>(hi);
  *reinterpret_cast<uint4*>(outb + sstr + base) = *reinterpret_cast<const uint4*>(lo);
}

// ---------------------------------------------------------------------------
// K4: fused q/k/v conv (MFMA, 2-split bf16) + BN + LIF -> bit-packed spikes
//     + near-threshold flags for the exact fixer.
// ---------------------------------------------------------------------------
__global__ __launch_bounds__(256, 2) void k_qkv_mfma(
    const uchar* __restrict__ xsF, const uchar* __restrict__ wfq,
    const float* __restrict__ qga, const float* __restrict__ qbe, const float* __restrict__ qme, const float* __restrict__ qva,
    const float* __restrict__ kga, const float* __restrict__ kbe, const float* __restrict__ kme, const float* __restrict__ kva,
    const float* __restrict__ vga, const float* __restrict__ vbe, const float* __restrict__ vme, const float* __restrict__ vva,
    ushort* __restrict__ qp, uint* __restrict__ flags) {
  __shared__ short lsB[4][8][64][8];  // 32KB
  const int tid = threadIdx.x;
  const int w = tid >> 6, lane = tid & 63;
  const int lhi = lane >> 4, llo = lane & 15;
  const int wr = w >> 1, wc = w & 1;
  const int oc0 = blockIdx.x * 64;
  const int ntile = blockIdx.y;
  const int b = blockIdx.z;
  const int sel = oc0 >> 8;
  const float* G  = sel == 0 ? qga : (sel == 1 ? kga : vga);
  const float* Be = sel == 0 ? qbe : (sel == 1 ? kbe : vbe);
  const float* Mn = sel == 0 ? qme : (sel == 1 ? kme : vme);
  const float* Vr = sel == 0 ? qva : (sel == 1 ? kva : vva);

  s16x8 wfr[2][2][8];
#pragma unroll
  for (int s = 0; s < 2; ++s)
#pragma unroll
    for (int mf = 0; mf < 2; ++mf) {
      const int ob = blockIdx.x * 4 + wr * 2 + mf;
#pragma unroll
      for (int ks = 0; ks < 8; ++ks)
        wfr[s][mf][ks] = *reinterpret_cast<const s16x8*>(
            wfq + ((((size_t)s * 48 + ob) * 8 + ks) * 64 + lane) * 16);
    }

  float inv8[2][4], mean8[2][4], beta8[2][4];
#pragma unroll
  for (int mf = 0; mf < 2; ++mf)
#pragma unroll
    for (int r = 0; r < 4; ++r) {
      const int ocb = (oc0 & 255) + wr * 32 + mf * 16 + lhi * 4 + r;
      inv8[mf][r] = G[ocb] / sqrtf(Vr[ocb] + EPSf);
      mean8[mf][r] = Mn[ocb];
      beta8[mf][r] = Be[ocb];
    }

  float vst[2][2][4];
#pragma unroll
  for (int mf = 0; mf < 2; ++mf)
#pragma unroll
    for (int nf = 0; nf < 2; ++nf)
#pragma unroll
      for (int r = 0; r < 4; ++r) vst[mf][nf][r] = 0.f;
  uint fl = 0;

  for (int t = 0; t < TT; ++t) {
    __syncthreads();
    const uchar* src = xsF + (((size_t)(t * BB + b) * 16 + ntile * 4) * 8192);
#pragma unroll
    for (int k2 = 0; k2 < 8; ++k2) {
      const int chunk = w * 8 + k2;
      gload_lds16(src + (size_t)chunk * 1024 + lane * 16,
                  reinterpret_cast<char*>(&lsB[0][0][0][0]) + chunk * 1024);
    }
    __syncthreads();

    f32x4 acc[2][2];
#pragma unroll
    for (int mf = 0; mf < 2; ++mf)
#pragma unroll
      for (int nf = 0; nf < 2; ++nf) acc[mf][nf] = (f32x4){0.f, 0.f, 0.f, 0.f};

#pragma unroll
    for (int ks = 0; ks < 8; ++ks) {
      s16x8 b0 = *reinterpret_cast<const s16x8*>(&lsB[wc * 2][ks][lane][0]);
      s16x8 b1 = *reinterpret_cast<const s16x8*>(&lsB[wc * 2 + 1][ks][lane][0]);
#pragma unroll
      for (int s = 0; s < 2; ++s)
#pragma unroll
        for (int mf = 0; mf < 2; ++mf) {
          acc[mf][0] = __builtin_amdgcn_mfma_f32_16x16x32_bf16(wfr[s][mf][ks], b0, acc[mf][0], 0, 0, 0);
          acc[mf][1] = __builtin_amdgcn_mfma_f32_16x16x32_bf16(wfr[s][mf][ks], b1, acc[mf][1], 0, 0, 0);
        }
    }

    ushort* qrow = qp + (size_t)(t * BB + b) * 768 * 16;
#pragma unroll
    for (int mf = 0; mf < 2; ++mf)
#pragma unroll
      for (int nf = 0; nf < 2; ++nf)
#pragma unroll
        for (int r = 0; r < 4; ++r) {
          float y = (acc[mf][nf][r] - mean8[mf][r]) * inv8[mf][r] + beta8[mf][r];
          float v = vst[mf][nf][r];
          v = v + (y - v) * 0.5f;
          const bool sp = (v >= 1.0f);
          if (fabsf(v - 1.0f) < MARGINf) fl |= 1u << ((mf * 2 + nf) * 4 + r);
          const unsigned long long m = __ballot(sp);
          if (llo == r) {
            const int oc = oc0 + wr * 32 + mf * 16 + lhi * 4 + r;
            const int nw = ntile * 4 + wc * 2 + nf;
            qrow[(size_t)oc * 16 + nw] = (ushort)((m >> (lhi * 16)) & 0xFFFFull);
          }
          vst[mf][nf][r] = sp ? 0.f : v;
        }
  }

  if (fl) {
    const int cnt = __popc(fl);
    uint base = atomicAdd(flags, (uint)cnt);
#pragma unroll
    for (int mf = 0; mf < 2; ++mf)
#pragma unroll
      for (int nf = 0; nf < 2; ++nf)
#pragma unroll
        for (int r = 0; r < 4; ++r)
          if (fl & (1u << ((mf * 2 + nf) * 4 + r))) {
            const int oc = oc0 + wr * 32 + mf * 16 + lhi * 4 + r;
            const int n = ntile * 64 + wc * 32 + nf * 16 + llo;
            if (base < FLAG_CAP) flags[4 + base] = (((uint)(b << 10) | (uint)oc) << 8) | (uint)n;
            base++;
          }
  }
}

// ---------------------------------------------------------------------------
// K5: exact fixer on packed spike bits. Per flagged element: 8 independent
// uint4 loads (whole spike footprint), then 64 affine float4 W loads feeding
// acc = fmaf(w_c, (float)bit_c, acc) ascending-c — bitwise the reference chain.
// ---------------------------------------------------------------------------
__global__ __launch_bounds__(256) void k_fix(
    const uchar* __restrict__ xsP,
    const float* __restrict__ qw, const float* __restrict__ kw, const float* __restrict__ vw,
    const float* __restrict__ qga, const float* __restrict__ qbe, const float* __restrict__ qme, const float* __restrict__ qva,
    const float* __restrict__ kga, const float* __restrict__ kbe, const float* __restrict__ kme, const float* __restrict__ kva,
    const float* __restrict__ vga, const float* __restrict__ vbe, const float* __restrict__ vme, const float* __restrict__ vva,
    uint* __restrict__ qp32, const uint* __restrict__ flags) {
#pragma clang fp contract(off)
  const uint cnt = min(flags[0], FLAG_CAP);
  for (uint i = blockIdx.x * 256 + threadIdx.x; i < cnt; i += gridDim.x * 256) {
    const uint e = flags[4 + i];
    const int n = e & 255;
    const int oc = (e >> 8) & 1023;
    const int b = e >> 18;
    const int sel = oc >> 8, ocl = oc & 255;
    const float* W = (sel == 0 ? qw : (sel == 1 ? kw : vw)) + (size_t)ocl * CC;
    const float* G  = sel == 0 ? qga : (sel == 1 ? kga : vga);
    const float* Be = sel == 0 ? qbe : (sel == 1 ? kbe : vbe);
    const float* Mn = sel == 0 ? qme : (sel == 1 ? kme : vme);
    const float* Vr = sel == 0 ? qva : (sel == 1 ? kva : vva);

    // load all spike bits for (b,n) across t: 8x uint4, independent
    uint bw[4][8];
#pragma unroll
    for (int t = 0; t < TT; ++t) {
      const uint4* p = reinterpret_cast<const uint4*>(
          xsP + (((size_t)(t * BB + b) * NN + n) << 5));
      uint4 a = p[0], c4 = p[1];
      bw[t][0] = a.x;  bw[t][1] = a.y;  bw[t][2] = a.z;  bw[t][3] = a.w;
      bw[t][4] = c4.x; bw[t][5] = c4.y; bw[t][6] = c4.z; bw[t][7] = c4.w;
    }

    const float4* W4 = reinterpret_cast<const float4*>(W);
    float a0 = 0.f, a1 = 0.f, a2 = 0.f, a3 = 0.f;
#pragma unroll
    for (int g = 0; g < 32; ++g) {  // byte group: c = g*8 + j
      const float4 w0 = W4[2 * g];
      const float4 w1 = W4[2 * g + 1];
      const uint s0 = bw[0][g >> 2] >> ((g & 3) * 8);
      const uint s1 = bw[1][g >> 2] >> ((g & 3) * 8);
      const uint s2 = bw[2][g >> 2] >> ((g & 3) * 8);
      const uint s3 = bw[3][g >> 2] >> ((g & 3) * 8);
      const float wv[8] = {w0.x, w0.y, w0.z, w0.w, w1.x, w1.y, w1.z, w1.w};
#pragma unroll
      for (int j = 0; j < 8; ++j) {
        a0 = fmaf(wv[j], (float)((s0 >> j) & 1u), a0);
        a1 = fmaf(wv[j], (float)((s1 >> j) & 1u), a1);
        a2 = fmaf(wv[j], (float)((s2 >> j) & 1u), a2);
        a3 = fmaf(wv[j], (float)((s3 >> j) & 1u), a3);
      }
    }
    float accs[4] = {a0, a1, a2, a3};

    const float inv = G[ocl] / sqrtf(Vr[ocl] + EPSf);
    const float mean = Mn[ocl], beta = Be[ocl];
    float v = 0.f;
#pragma unroll
    for (int t = 0; t < TT; ++t) {
      float xm = accs[t] - mean;
      float y = xm * inv;
      y = y + beta;
      float d = (y - v) * 0.5f;
      v = v + d;
      const bool sp = (v >= 1.0f);
      const size_t widx = ((size_t)(t * BB + b) * 768 + oc) * 8 + (n >> 5);
      const uint bit = 1u << (n & 31);
      if (sp) atomicOr(&qp32[widx], bit);
      else atomicAnd(&qp32[widx], ~bit);
      if (sp) v = 0.f;
    }
  }
}

// ---------------------------------------------------------------------------
// K6: attention Q(K^T V)*2scale + LIF via popcount; writes proj B-fragments.
// ---------------------------------------------------------------------------
__global__ __launch_bounds__(256) void k_attn(const ushort* __restrict__ qp,
                                              uchar* __restrict__ attnF) {
  __shared__ uint Qb[32][8], Kb[32][8], Vb[32][8];
  __shared__ int KtV[32][36];
  const int tid = threadIdx.x;
  const int b = blockIdx.x >> 3;
  const int h = blockIdx.x & 7;
  const int ch = tid >> 3, wv = tid & 7;
  const int n = tid;

  float vst[32];
#pragma unroll
  for (int j = 0; j < 32; ++j) vst[j] = 0.f;

  for (int t = 0; t < TT; ++t) {
    __syncthreads();
    const ushort* base = qp + (size_t)(t * BB + b) * 768 * 16;
    Qb[ch][wv] = *reinterpret_cast<const uint*>(base + (size_t)(h * 32 + ch) * 16 + wv * 2);
    Kb[ch][wv] = *reinterpret_cast<const uint*>(base + (size_t)(256 + h * 32 + ch) * 16 + wv * 2);
    Vb[ch][wv] = *reinterpret_cast<const uint*>(base + (size_t)(512 + h * 32 + ch) * 16 + wv * 2);
    __syncthreads();
#pragma unroll
    for (int p = 0; p < 4; ++p) {
      const int ee = tid + p * 256;
      const int ii = ee >> 5, jj = ee & 31;
      int s = 0;
#pragma unroll
      for (int ww = 0; ww < 8; ++ww) s += __popc(Kb[ii][ww] & Vb[jj][ww]);
      KtV[ii][jj] = s;
    }
    __syncthreads();
    int acc[32];
#pragma unroll
    for (int j = 0; j < 32; ++j) acc[j] = 0;
    for (int ii = 0; ii < 32; ++ii) {
      const uint qbit = (Qb[ii][n >> 5] >> (n & 31)) & 1u;
      if (qbit) {
        const int4* row = reinterpret_cast<const int4*>(&KtV[ii][0]);
#pragma unroll
        for (int j4 = 0; j4 < 8; ++j4) {
          int4 kk = row[j4];
          acc[j4 * 4 + 0] += kk.x;
          acc[j4 * 4 + 1] += kk.y;
          acc[j4 * 4 + 2] += kk.z;
          acc[j4 * 4 + 3] += kk.w;
        }
      }
    }
    uint smask = 0;
    {
#pragma clang fp contract(off)
#pragma unroll
      for (int j = 0; j < 32; ++j) {
        float y = (float)acc[j] * MULTf;
        float v = vst[j];
        float d = (y - v) * 0.5f;
        v = v + d;
        const bool sp = (v >= 1.0f);
        if (sp) smask |= 1u << j;
        vst[j] = sp ? 0.f : v;
      }
    }
    uint4* dst = reinterpret_cast<uint4*>(attnF) + (size_t)(t * BB + b) * 8192 + (n >> 4) * 512 + h * 64;
#pragma unroll
    for (int lhi = 0; lhi < 4; ++lhi) {
      uint wds[4];
#pragma unroll
      for (int p = 0; p < 4; ++p) {
        const uint b0 = (smask >> (lhi * 8 + p * 2)) & 1u;
        const uint b1 = (smask >> (lhi * 8 + p * 2 + 1)) & 1u;
        wds[p] = (b0 ? 0x3F80u : 0u) | (b1 ? 0x3F800000u : 0u);
      }
      uint4 o; o.x = wds[0]; o.y = wds[1]; o.z = wds[2]; o.w = wds[3];
      dst[lhi * 16 + (n & 15)] = o;
    }
  }
}

// ---------------------------------------------------------------------------
// K7: proj conv (MFMA, 2-split) + BN -> f32 out.
// ---------------------------------------------------------------------------
__global__ __launch_bounds__(256, 2) void k_proj_mfma(
    const uchar* __restrict__ attnF, const uchar* __restrict__ wfp,
    const float* __restrict__ pga, const float* __restrict__ pbe,
    const float* __restrict__ pme, const float* __restrict__ pva,
    float* __restrict__ out) {
  __shared__ short lsB[4][8][64][8];
  const int tid = threadIdx.x;
  const int w = tid >> 6, lane = tid & 63;
  const int lhi = lane >> 4, llo = lane & 15;
  const int wr = w >> 1, wc = w & 1;
  const int oc0 = blockIdx.x * 64;
  const int ntile = blockIdx.y;
  const int tb = blockIdx.z;

  s16x8 wfr[2][2][8];
#pragma unroll
  for (int s = 0; s < 2; ++s)
#pragma unroll
    for (int mf = 0; mf < 2; ++mf) {
      const int ob = blockIdx.x * 4 + wr * 2 + mf;
#pragma unroll
      for (int ks = 0; ks < 8; ++ks)
        wfr[s][mf][ks] = *reinterpret_cast<const s16x8*>(
            wfp + ((((size_t)s * 16 + ob) * 8 + ks) * 64 + lane) * 16);
    }

  float inv8[2][4], mean8[2][4], beta8[2][4];
#pragma unroll
  for (int mf = 0; mf < 2; ++mf)
#pragma unroll
    for (int r = 0; r < 4; ++r) {
      const int ocb = oc0 + wr * 32 + mf * 16 + lhi * 4 + r;
      inv8[mf][r] = pga[ocb] / sqrtf(pva[ocb] + EPSf);
      mean8[mf][r] = pme[ocb];
      beta8[mf][r] = pbe[ocb];
    }

  const uchar* src = attnF + (((size_t)tb * 16 + ntile * 4) * 8192);
#pragma unroll
  for (int k2 = 0; k2 < 8; ++k2) {
    const int chunk = w * 8 + k2;
    gload_lds16(src + (size_t)chunk * 1024 + lane * 16,
                reinterpret_cast<char*>(&lsB[0][0][0][0]) + chunk * 1024);
  }
  __syncthreads();

  f32x4 acc[2][2];
#pragma unroll
  for (int mf = 0; mf < 2; ++mf)
#pragma unroll
    for (int nf = 0; nf < 2; ++nf) acc[mf][nf] = (f32x4){0.f, 0.f, 0.f, 0.f};

#pragma unroll
  for (int ks = 0; ks < 8; ++ks) {
    s16x8 b0 = *reinterpret_cast<const s16x8*>(&lsB[wc * 2][ks][lane][0]);
    s16x8 b1 = *reinterpret_cast<const s16x8*>(&lsB[wc * 2 + 1][ks][lane][0]);
#pragma unroll
    for (int s = 0; s < 2; ++s)
#pragma unroll
      for (int mf = 0; mf < 2; ++mf) {
        acc[mf][0] = __builtin_amdgcn_mfma_f32_16x16x32_bf16(wfr[s][mf][ks], b0, acc[mf][0], 0, 0, 0);
        acc[mf][1] = __builtin_amdgcn_mfma_f32_16x16x32_bf16(wfr[s][mf][ks], b1, acc[mf][1], 0, 0, 0);
      }
  }

#pragma unroll
  for (int mf = 0; mf < 2; ++mf)
#pragma unroll
    for (int nf = 0; nf < 2; ++nf)
#pragma unroll
      for (int r = 0; r < 4; ++r) {
        const int oc = oc0 + wr * 32 + mf * 16 + lhi * 4 + r;
        const int nn = ntile * 64 + wc * 32 + nf * 16 + llo;
        float y = (acc[mf][nf][r] - mean8[mf][r]) * inv8[mf][r] + beta8[mf][r];
        out[((size_t)tb * CC + oc) * NN + nn] = y;
      }
}

// ---------------------------------------------------------------------------
extern "C" void kernel_launch(void* const* d_in, const int* in_sizes, int n_in,
                              void* d_out, int out_size, void* d_ws, size_t ws_size,
                              hipStream_t stream) {
  const float* x = (const float*)d_in[0];
  const float* q_w = (const float*)d_in[1];
  const float* q_g = (const float*)d_in[2];
  const float* q_b = (const float*)d_in[3];
  const float* q_m = (const float*)d_in[4];
  const float* q_v = (const float*)d_in[5];
  const float* k_w = (const float*)d_in[6];
  const float* k_g = (const float*)d_in[7];
  const float* k_b = (const float*)d_in[8];
  const float* k_m = (const float*)d_in[9];
  const float* k_v = (const float*)d_in[10];
  const float* v_w = (const float*)d_in[11];
  const float* v_g = (const float*)d_in[12];
  const float* v_b = (const float*)d_in[13];
  const float* v_m = (const float*)d_in[14];
  const float* v_v = (const float*)d_in[15];
  const float* p_w = (const float*)d_in[16];
  const float* p_g = (const float*)d_in[17];
  const float* p_b = (const float*)d_in[18];
  const float* p_m = (const float*)d_in[19];
  const float* p_v = (const float*)d_in[20];

  uchar* ws = (uchar*)d_ws;
  uchar* xsF  = ws;                         // 16 MiB frags (reused as attnF)
  ushort* qp  = (ushort*)(ws + 16777216);   // 3 MiB packed q/k/v spikes
  uchar* wfq  = ws + 19922944;              // 768 KiB
  uchar* wfp  = ws + 20709376;              // 256 KiB
  uint* flags = (uint*)(ws + 20971520);     // 16 B counter + list (2 MiB)
  uchar* xsP  = ws + 23068672;              // 1 MiB bit-packed xs spikes

  hipMemsetAsync(flags, 0, 16, stream);

  k_prep_w<<<dim3(128), 256, 0, stream>>>(q_w, k_w, v_w, p_w, wfq, wfp);
  k_lif_frag<<<dim3(4, 8, 32), 256, 0, stream>>>(x, xsF, xsP);
  k_qkv_mfma<<<dim3(12, 4, 32), 256, 0, stream>>>(xsF, wfq,
                                                  q_g, q_b, q_m, q_v,
                                                  k_g, k_b, k_m, k_v,
                                                  v_g, v_b, v_m, v_v,
                                                  qp, flags);
  k_fix<<<dim3(64), 256, 0, stream>>>(xsP, q_w, k_w, v_w,
                                      q_g, q_b, q_m, q_v,
                                      k_g, k_b, k_m, k_v,
                                      v_g, v_b, v_m, v_v,
                                      (uint*)qp, flags);
  k_attn<<<dim3(256), 256, 0, stream>>>(qp, xsF /* attnF shares region */);
  k_proj_mfma<<<dim3(4, 4, 128), 256, 0, stream>>>(xsF, wfp, p_g, p_b, p_m, p_v,
                                                   (float*)d_out);
}